// Round 8
// baseline (2749.355 us; speedup 1.0000x reference)
//
#include <hip/hip_runtime.h>
#include <hip/hip_bf16.h>

typedef __hip_bfloat16 bf16;

#define B_ 2
#define T_ 1024
#define C_ 1024
#define H_ 16
#define N_ 64

using short8 = __attribute__((ext_vector_type(8))) short;
using f32x4 = __attribute__((ext_vector_type(4))) float;

__device__ __forceinline__ float us2f(unsigned short u) {
  return __uint_as_float(((unsigned int)u) << 16);
}
__device__ __forceinline__ float bs2f(short s) {
  return __uint_as_float(((unsigned int)(unsigned short)s) << 16);
}
__device__ __forceinline__ bf16 f2bf(float f) { return __float2bfloat16(f); }
__device__ __forceinline__ float sigmoidf_(float x) { return 1.0f / (1.0f + expf(-x)); }
__device__ __forceinline__ float softplusf_(float x) {
  return fmaxf(x, 0.0f) + log1pf(expf(-fabsf(x)));
}

// ---------------- K0: fused weight fp32->bf16 conversion (big weights) ------
__global__ __launch_bounds__(256) void cvt_weights_kernel(
    const float* __restrict__ s0, const float* __restrict__ s1,
    const float* __restrict__ s2, const float* __restrict__ s3,
    const float* __restrict__ s4, const float* __restrict__ s5,
    const float* __restrict__ s6,
    bf16* __restrict__ d0, bf16* __restrict__ d1, bf16* __restrict__ d2,
    bf16* __restrict__ d3, bf16* __restrict__ d4, bf16* __restrict__ d5,
    bf16* __restrict__ d6) {
  long i4 = (long)blockIdx.x * 256 + threadIdx.x;
  const float* s; bf16* d; long off;
  if (i4 < 32768) { s = s0; d = d0; off = i4; }
  else if (i4 < 294912) { s = s1; d = d1; off = i4 - 32768; }
  else if (i4 < 327680) { s = s2; d = d2; off = i4 - 294912; }
  else if (i4 < 360448) { s = s3; d = d3; off = i4 - 327680; }
  else if (i4 < 622592) { s = s4; d = d4; off = i4 - 360448; }
  else if (i4 < 884736) { s = s5; d = d5; off = i4 - 622592; }
  else { s = s6; d = d6; off = i4 - 884736; }
  float4 v = *(const float4*)(s + off * 4);
  d[off * 4 + 0] = f2bf(v.x);
  d[off * 4 + 1] = f2bf(v.y);
  d[off * 4 + 2] = f2bf(v.z);
  d[off * 4 + 3] = f2bf(v.w);
}

// ---------------- K0b: pack small LoRA-1 weights to bf16 --------------------
// wsk[32][1024]  = [tkw1(16) | mkw1(16)]
// wswa[96][1024] = [tdw1(64) | taw1(16) | maw1(16)]
__global__ __launch_bounds__(256) void cvt_small_kernel(
    const float* __restrict__ tkw1, const float* __restrict__ mkw1,
    const float* __restrict__ tdw1, const float* __restrict__ taw1,
    const float* __restrict__ maw1,
    bf16* __restrict__ wsk, bf16* __restrict__ wswa) {
  long i4 = (long)blockIdx.x * 256 + threadIdx.x;  // < 32768
  const float* s; bf16* d; long so, dof;
  if (i4 < 4096) { s = tkw1; so = i4; d = wsk; dof = i4; }
  else if (i4 < 8192) { s = mkw1; so = i4 - 4096; d = wsk; dof = i4; }
  else if (i4 < 24576) { s = tdw1; so = i4 - 8192; d = wswa; dof = i4 - 8192; }
  else if (i4 < 28672) { s = taw1; so = i4 - 24576; d = wswa; dof = i4 - 8192; }
  else { s = maw1; so = i4 - 28672; d = wswa; dof = i4 - 8192; }
  float4 v = *(const float4*)(s + so * 4);
  d[dof * 4 + 0] = f2bf(v.x);
  d[dof * 4 + 1] = f2bf(v.y);
  d[dof * 4 + 2] = f2bf(v.z);
  d[dof * 4 + 3] = f2bf(v.w);
}

// ---------------- K0c: LoRA-2 weights to bf16 -------------------------------
// ranges (f4): tmw2 32768 | tdw2 16384 | tkw2 4096 | taw2 4096 | maw2 4096 |
// mkw2 4096  (total 65536)
__global__ __launch_bounds__(256) void cvt_small2_kernel(
    const float* __restrict__ tmw2, const float* __restrict__ tdw2,
    const float* __restrict__ tkw2, const float* __restrict__ taw2,
    const float* __restrict__ maw2, const float* __restrict__ mkw2,
    bf16* __restrict__ tmw2b, bf16* __restrict__ tdw2b,
    bf16* __restrict__ tkw2b, bf16* __restrict__ taw2b,
    bf16* __restrict__ maw2b, bf16* __restrict__ mkw2b) {
  long i4 = (long)blockIdx.x * 256 + threadIdx.x;  // < 65536
  const float* s; bf16* d; long off;
  if (i4 < 32768) { s = tmw2; d = tmw2b; off = i4; }
  else if (i4 < 49152) { s = tdw2; d = tdw2b; off = i4 - 32768; }
  else if (i4 < 53248) { s = tkw2; d = tkw2b; off = i4 - 49152; }
  else if (i4 < 57344) { s = taw2; d = taw2b; off = i4 - 53248; }
  else if (i4 < 61440) { s = maw2; d = maw2b; off = i4 - 57344; }
  else { s = mkw2; d = mkw2b; off = i4 - 61440; }
  float4 v = *(const float4*)(s + off * 4);
  d[off * 4 + 0] = f2bf(v.x);
  d[off * 4 + 1] = f2bf(v.y);
  d[off * 4 + 2] = f2bf(v.z);
  d[off * 4 + 3] = f2bf(v.w);
}

// ---------------- K1: token shift (writes xx f32, xxx bf16) -----------------
__global__ __launch_bounds__(256) void shift_kernel(
    const float* __restrict__ x, const float* __restrict__ tmx,
    float* __restrict__ xx, bf16* __restrict__ xxxb) {
  long idx = (long)blockIdx.x * 256 + threadIdx.x;  // < B*T*C
  int c = (int)(idx & (C_ - 1));
  int t = (int)((idx >> 10) & (T_ - 1));
  float xv = x[idx];
  float xp = (t > 0) ? x[idx - C_] : 0.0f;
  float d = xp - xv;
  xx[idx] = d;
  xxxb[idx] = f2bf(xv + d * tmx[c]);
}

// ---------------- MFMA GEMM: C = A(bf16 MxK) * W^T (W bf16 NxK) -------------
// 64x64 block tile, 4 waves; BK=64 per barrier pair. N-guarded.
// actN: columns < actN get tanh.
__global__ __launch_bounds__(256) void gemm_mfma_kernel(
    const bf16* __restrict__ A, const bf16* __restrict__ W,
    float* __restrict__ Cf, bf16* __restrict__ Cb,
    int M, int N, int K, int actN) {
  __shared__ __align__(16) bf16 As[64][72];  // 144B row stride, 16B aligned
  __shared__ __align__(16) bf16 Ws[64][72];
  int tid = threadIdx.x;
  int m0 = blockIdx.y << 6, n0 = blockIdx.x << 6;
  int srow = tid >> 2, skg = (tid & 3) << 4;   // staging: row, 16 bf16 per thread
  int wv = tid >> 6, lane = tid & 63;
  int fr = lane & 15, fq = lane >> 4;
  f32x4 acc0 = {0.f, 0.f, 0.f, 0.f}, acc1 = acc0, acc2 = acc0, acc3 = acc0;
  bool wok = (n0 + srow) < N;
  const bf16* Ap = A + (long)(m0 + srow) * K + skg;
  const bf16* Wp = W + (long)(n0 + srow) * K + skg;
  short8 zz = {0, 0, 0, 0, 0, 0, 0, 0};
  for (int k0 = 0; k0 < K; k0 += 64) {
    *(short8*)&As[srow][skg] = *(const short8*)(Ap + k0);
    *(short8*)&As[srow][skg + 8] = *(const short8*)(Ap + k0 + 8);
    *(short8*)&Ws[srow][skg] = wok ? *(const short8*)(Wp + k0) : zz;
    *(short8*)&Ws[srow][skg + 8] = wok ? *(const short8*)(Wp + k0 + 8) : zz;
    __syncthreads();
#pragma unroll
    for (int kk = 0; kk < 2; kk++) {
      int ko = (fq << 3) + (kk << 5);
      short8 af = *(const short8*)&As[(wv << 4) + fr][ko];
      short8 b0 = *(const short8*)&Ws[fr][ko];
      short8 b1 = *(const short8*)&Ws[16 + fr][ko];
      short8 b2 = *(const short8*)&Ws[32 + fr][ko];
      short8 b3 = *(const short8*)&Ws[48 + fr][ko];
      acc0 = __builtin_amdgcn_mfma_f32_16x16x32_bf16(af, b0, acc0, 0, 0, 0);
      acc1 = __builtin_amdgcn_mfma_f32_16x16x32_bf16(af, b1, acc1, 0, 0, 0);
      acc2 = __builtin_amdgcn_mfma_f32_16x16x32_bf16(af, b2, acc2, 0, 0, 0);
      acc3 = __builtin_amdgcn_mfma_f32_16x16x32_bf16(af, b3, acc3, 0, 0, 0);
    }
    __syncthreads();
  }
  // C/D layout: col = lane&15, row = (lane>>4)*4 + reg
  int orow = m0 + (wv << 4) + (fq << 2);
  int ocol = n0 + fr;
  f32x4 av[4] = {acc0, acc1, acc2, acc3};
#pragma unroll
  for (int nt = 0; nt < 4; nt++) {
    int col = ocol + (nt << 4);
    if (col < N) {
#pragma unroll
      for (int r = 0; r < 4; r++) {
        float vvv = av[nt][r];
        if (col < actN) vvv = tanhf(vvv);
        long oi = (long)(orow + r) * N + col;
        if (Cb) Cb[oi] = f2bf(vvv); else Cf[oi] = vvv;
      }
    }
  }
}

// ---------------- K3: deltas + build xrg/xwa/xk/xv (bf16 out) ---------------
__global__ __launch_bounds__(256) void mix4_kernel(
    const float* __restrict__ x, const float* __restrict__ xx,
    const float* __restrict__ mix, const float* __restrict__ tmaa,
    const bf16* __restrict__ w2b,
    bf16* __restrict__ xrg, bf16* __restrict__ xwa,
    bf16* __restrict__ xk, bf16* __restrict__ xv) {
  int m = blockIdx.x;
  int tid = threadIdx.x;
  __shared__ float mrow[128];
  if (tid < 128) mrow[tid] = mix[(long)m * 128 + tid];
  __syncthreads();
#pragma unroll
  for (int cc = 0; cc < 4; cc++) {
    int c = tid + (cc << 8);
    long off = (long)m * C_ + c;
    float xb = x[off];
    float xxv = xx[off];
    float res[4];
#pragma unroll
    for (int f = 0; f < 4; f++) {
      const short8* wp = (const short8*)(w2b + (((long)f * C_ + c) << 5));
      float dl = 0.f;
#pragma unroll
      for (int d8 = 0; d8 < 4; d8++) {
        short8 u = wp[d8];
        int db = (f << 5) + (d8 << 3);
#pragma unroll
        for (int e = 0; e < 8; e++) dl += mrow[db + e] * bs2f(u[e]);
      }
      res[f] = xb + xxv * (tmaa[f * C_ + c] + dl);
    }
    xrg[off] = f2bf(res[0]); xwa[off] = f2bf(res[1]);
    xk[off] = f2bf(res[2]); xv[off] = f2bf(res[3]);
  }
}

// ---------------- K5: stage-2 small GEMMs + gates + per-head kk norm --------
// out1[m][32] = [kk1(tanh,16) | mk1(16)]; out2[m][96] = [w1(tanh,64)|a1(16)|ma1(16)]
__global__ __launch_bounds__(256) void fuse2_kernel(
    const float* __restrict__ kraw, const float* __restrict__ out1,
    const float* __restrict__ out2,
    const bf16* __restrict__ dw2, const bf16* __restrict__ kkw2,
    const bf16* __restrict__ aw2, const bf16* __restrict__ maw2,
    const bf16* __restrict__ mkw2,
    const float* __restrict__ tdec, const float* __restrict__ taa,
    const float* __restrict__ tma, const float* __restrict__ tmk,
    float* __restrict__ ew, float* __restrict__ kfin,
    float* __restrict__ kkn, float* __restrict__ bbo) {
  int m = blockIdx.x, tid = threadIdx.x;
  __shared__ float w1r[64], kk1r[16], a1r[16], ma1r[16], mk1r[16];
  if (tid < 64) w1r[tid] = out2[(long)m * 96 + tid];
  else if (tid < 80) kk1r[tid - 64] = out1[(long)m * 32 + (tid - 64)];
  else if (tid < 96) a1r[tid - 80] = out2[(long)m * 96 + 64 + (tid - 80)];
  else if (tid < 112) ma1r[tid - 96] = out2[(long)m * 96 + 80 + (tid - 96)];
  else if (tid < 128) mk1r[tid - 112] = out1[(long)m * 32 + 16 + (tid - 112)];
  __syncthreads();
  float kkp[4], av[4], wv[4], kr[4], mkv[4];
  float sumsq = 0.f;
#pragma unroll
  for (int j = 0; j < 4; j++) {
    int c = (tid << 2) + j;
    long off = (long)m * C_ + c;
    float wd = 0.f;
    const short8* dp = (const short8*)(dw2 + ((long)c << 6));
#pragma unroll
    for (int d8 = 0; d8 < 8; d8++) {
      short8 u = dp[d8];
      int db = d8 << 3;
#pragma unroll
      for (int e = 0; e < 8; e++) wd += w1r[db + e] * bs2f(u[e]);
    }
    float w = -softplusf_(-(tdec[c] + wd)) - 0.5f;
    wv[j] = w;
    float kd = 0.f, ad = 0.f, mad = 0.f, mkd = 0.f;
    const short8* kp = (const short8*)(kkw2 + ((long)c << 4));
    const short8* ap = (const short8*)(aw2 + ((long)c << 4));
    const short8* mp = (const short8*)(maw2 + ((long)c << 4));
    const short8* qp = (const short8*)(mkw2 + ((long)c << 4));
#pragma unroll
    for (int d8 = 0; d8 < 2; d8++) {
      short8 u1 = kp[d8], u2 = ap[d8], u3 = mp[d8], u4 = qp[d8];
      int db = d8 << 3;
#pragma unroll
      for (int e = 0; e < 8; e++) {
        kd += kk1r[db + e] * bs2f(u1[e]);
        ad += a1r[db + e] * bs2f(u2[e]);
        mad += ma1r[db + e] * bs2f(u3[e]);
        mkd += mk1r[db + e] * bs2f(u4[e]);
      }
    }
    float krw = kraw[off];
    float kkpre = krw + kd;
    kkp[j] = kkpre;
    sumsq += kkpre * kkpre;
    float a = sigmoidf_(taa[c] + ad);
    av[j] = a;
    float ma = sigmoidf_(tma[c] + mad);
    float mk = sigmoidf_(tmk[c] + mkd);
    mkv[j] = mk;
    kr[j] = krw * (ma + a * (1.f - ma));
  }
  sumsq += __shfl_xor(sumsq, 1);
  sumsq += __shfl_xor(sumsq, 2);
  sumsq += __shfl_xor(sumsq, 4);
  sumsq += __shfl_xor(sumsq, 8);
  float rn = 1.0f / fmaxf(sqrtf(sumsq), 1e-12f);
#pragma unroll
  for (int j = 0; j < 4; j++) {
    int c = (tid << 2) + j;
    long off = (long)m * C_ + c;
    float kknv = kkp[j] * rn;
    kkn[off] = kknv;
    bbo[off] = -kknv * av[j];
    ew[off] = expf(wv[j]);
    kfin[off] = kr[j] * expf(wv[j] * mkv[j]);
  }
}

// ---------------- K6: RWKV-7 scan, co-located waves -------------------------
// 16 blocks x 512 threads = 8 waves/block: waves 0-3 -> (b,h) A rowgroups 0-3,
// waves 4-7 -> (b,h) B. All 4 waves of a stream share one CU's L1 (identical
// kk/ew/k/bb/r lines); 2 streams/SIMD cross-hide latency. lane=(r<<2)|q:
// row = rg*16+r, 16 consecutive keys [q*16,q*16+16). shfl_xor 1,2 = quad_perm.
__global__ __launch_bounds__(512) void scan_kernel(
    const float* __restrict__ rB, const float* __restrict__ ewB,
    const float* __restrict__ kB, const float* __restrict__ vB,
    const float* __restrict__ kkB, const float* __restrict__ bbB,
    float* __restrict__ yB) {
  int wave = threadIdx.x >> 6;       // 0..7
  int strm = wave >> 2;              // 0..1
  int rg = wave & 3;
  int bh = (blockIdx.x << 1) | strm; // 0..31
  int b = bh >> 4, h = bh & 15;
  int lane = threadIdx.x & 63;
  int r = lane >> 2, q = lane & 3;
  int row = (rg << 4) + r;
  int kq = q << 4;
  const long base = ((long)b * T_) * C_ + (h << 6);
  float S[16];
#pragma unroll
  for (int j = 0; j < 16; j++) S[j] = 0.f;
  float4 kk4[2][4], ew4[2][4], k4[2][4], bb4[2][4], r4[2][4];
  float v2[2];
#pragma unroll
  for (int i = 0; i < 2; i++) {
    long o = base + (long)i * C_ + kq;
#pragma unroll
    for (int jj = 0; jj < 4; jj++) {
      kk4[i][jj] = *(const float4*)(kkB + o + jj * 4);
      ew4[i][jj] = *(const float4*)(ewB + o + jj * 4);
      k4[i][jj] = *(const float4*)(kB + o + jj * 4);
      bb4[i][jj] = *(const float4*)(bbB + o + jj * 4);
      r4[i][jj] = *(const float4*)(rB + o + jj * 4);
    }
    v2[i] = vB[base + (long)i * C_ + row];
  }
  for (int t = 0; t < T_; t += 2) {
#pragma unroll
    for (int s = 0; s < 2; s++) {
      int tt = t + s;
      const float* ckk = (const float*)&kk4[s][0];
      const float* cew = (const float*)&ew4[s][0];
      const float* ck = (const float*)&k4[s][0];
      const float* cbb = (const float*)&bb4[s][0];
      const float* crr = (const float*)&r4[s][0];
      float cv = v2[s];
      // sab partial over 16 keys (4 independent chains)
      float p0 = 0, p1 = 0, p2 = 0, p3 = 0;
#pragma unroll
      for (int j = 0; j < 4; j++) {
        p0 += S[j] * ckk[j];
        p1 += S[4 + j] * ckk[4 + j];
        p2 += S[8 + j] * ckk[8 + j];
        p3 += S[12 + j] * ckk[12 + j];
      }
      float sab = (p0 + p1) + (p2 + p3);
      sab += __shfl_xor(sab, 1);
      sab += __shfl_xor(sab, 2);
      // state update + y partial
#pragma unroll
      for (int j = 0; j < 16; j++)
        S[j] = S[j] * cew[j] + sab * cbb[j] + cv * ck[j];
      float y0 = 0, y1 = 0, y2 = 0, y3 = 0;
#pragma unroll
      for (int j = 0; j < 4; j++) {
        y0 += S[j] * crr[j];
        y1 += S[4 + j] * crr[4 + j];
        y2 += S[8 + j] * crr[8 + j];
        y3 += S[12 + j] * crr[12 + j];
      }
      float y = (y0 + y1) + (y2 + y3);
      y += __shfl_xor(y, 1);
      y += __shfl_xor(y, 2);
      if (q == 0) yB[base + (long)tt * C_ + row] = y;
      // prefetch tt+2 into slot s
      int tl = tt + 2; if (tl > T_ - 1) tl = T_ - 1;
      long o = base + (long)tl * C_ + kq;
#pragma unroll
      for (int jj = 0; jj < 4; jj++) {
        kk4[s][jj] = *(const float4*)(kkB + o + jj * 4);
        ew4[s][jj] = *(const float4*)(ewB + o + jj * 4);
        k4[s][jj] = *(const float4*)(kB + o + jj * 4);
        bb4[s][jj] = *(const float4*)(bbB + o + jj * 4);
        r4[s][jj] = *(const float4*)(rB + o + jj * 4);
      }
      v2[s] = vB[base + (long)tl * C_ + row];
    }
  }
}

// ---------------- K7: GroupNorm + bonus + gate (bf16 out) -------------------
__global__ __launch_bounds__(256) void gnout_kernel(
    const float* __restrict__ y, const float* __restrict__ r,
    const float* __restrict__ kf, const float* __restrict__ v,
    const float* __restrict__ g,
    const float* __restrict__ lnw, const float* __restrict__ lnb,
    const float* __restrict__ fa, bf16* __restrict__ z) {
  int tid = threadIdx.x;
  int w = tid >> 6, lane = tid & 63;
  int gi = (blockIdx.x << 2) + w;  // (b*T+t)*H + h
  int h = gi & 15, mt = gi >> 4;
  long off = (long)mt * C_ + (h << 6) + lane;
  float yv = y[off];
  float s = yv;
  s += __shfl_xor(s, 1); s += __shfl_xor(s, 2); s += __shfl_xor(s, 4);
  s += __shfl_xor(s, 8); s += __shfl_xor(s, 16); s += __shfl_xor(s, 32);
  float mu = s * (1.0f / 64.0f);
  float d = yv - mu;
  float s2 = d * d;
  s2 += __shfl_xor(s2, 1); s2 += __shfl_xor(s2, 2); s2 += __shfl_xor(s2, 4);
  s2 += __shfl_xor(s2, 8); s2 += __shfl_xor(s2, 16); s2 += __shfl_xor(s2, 32);
  float var = s2 * (1.0f / 64.0f);
  int hc = (h << 6) + lane;
  float dot = r[off] * kf[off] * fa[hc];
  dot += __shfl_xor(dot, 1); dot += __shfl_xor(dot, 2); dot += __shfl_xor(dot, 4);
  dot += __shfl_xor(dot, 8); dot += __shfl_xor(dot, 16); dot += __shfl_xor(dot, 32);
  float yn = d * rsqrtf(var + 0.00064f) * lnw[hc] + lnb[hc];
  z[off] = f2bf((yn + dot * v[off]) * g[off]);
}

extern "C" void kernel_launch(void* const* d_in, const int* in_sizes, int n_in,
                              void* d_out, int out_size, void* d_ws, size_t ws_size,
                              hipStream_t stream) {
  const float* x = (const float*)d_in[0];
  const float* tmx = (const float*)d_in[1];
  const float* tmaa = (const float*)d_in[2];
  const float* tmw1 = (const float*)d_in[3];
  const float* tmw2 = (const float*)d_in[4];
  const float* tdec = (const float*)d_in[5];
  const float* tdw1 = (const float*)d_in[6];
  const float* tdw2 = (const float*)d_in[7];
  const float* taa5 = (const float*)d_in[8];
  const float* taw1 = (const float*)d_in[9];
  const float* taw2 = (const float*)d_in[10];
  const float* tkw1 = (const float*)d_in[11];
  const float* tkw2 = (const float*)d_in[12];
  const float* gw1 = (const float*)d_in[13];
  const float* gw2 = (const float*)d_in[14];
  const float* tmia = (const float*)d_in[15];
  const float* maw1 = (const float*)d_in[16];
  const float* maw2 = (const float*)d_in[17];
  const float* tmik = (const float*)d_in[18];
  const float* mkw1 = (const float*)d_in[19];
  const float* mkw2 = (const float*)d_in[20];
  const float* wrec = (const float*)d_in[21];
  const float* wkey = (const float*)d_in[22];
  const float* wval = (const float*)d_in[23];
  const float* wout = (const float*)d_in[24];
  const float* lnw = (const float*)d_in[25];
  const float* lnb = (const float*)d_in[26];
  const float* faaa = (const float*)d_in[27];

  const long MT = 2048, CC = 1024;
  char* base = (char*)d_ws;
  float* xx = (float*)base;    base += MT * CC * 4;   // also y
  bf16* xxxb = (bf16*)base;    base += MT * CC * 2;
  bf16* xrgb = (bf16*)base;    base += MT * CC * 2;   // ┐ kfin overlays (8MB)
  bf16* xwab = (bf16*)base;    base += MT * CC * 2;   // ┘
  bf16* xkb = (bf16*)base;     base += MT * CC * 2;   // ┐ kkn overlays (8MB)
  bf16* xvb = (bf16*)base;     base += MT * CC * 2;   // ┘
  float* rr = (float*)base;    base += MT * CC * 4;
  float* kraw = (float*)base;  base += MT * CC * 4;   // also ew
  float* vv = (float*)base;    base += MT * CC * 4;
  float* gg = (float*)base;    base += MT * CC * 4;
  float* bbo = (float*)base;   base += MT * CC * 4;
  float* mix = (float*)base;   base += MT * 128 * 4;
  bf16* g1b = (bf16*)base;     base += MT * 128 * 2;
  float* out1 = (float*)base;  base += MT * 32 * 4;   // [kk1|mk1]
  float* out2 = (float*)base;  base += MT * 96 * 4;   // [w1|a1|ma1]
  bf16* zb = (bf16*)base;      base += MT * CC * 2;
  bf16* tmw1b = (bf16*)base;   base += 128 * CC * 2;
  bf16* wrecb = (bf16*)base;   base += CC * CC * 2;
  bf16* gw1b = (bf16*)base;    base += 128 * CC * 2;
  bf16* gw2b = (bf16*)base;    base += CC * 128 * 2;
  bf16* wkeyb = (bf16*)base;   base += CC * CC * 2;
  bf16* wvalb = (bf16*)base;   base += CC * CC * 2;
  bf16* woutb = (bf16*)base;   base += CC * CC * 2;
  bf16* wskb = (bf16*)base;    base += 32 * CC * 2;
  bf16* wswab = (bf16*)base;   base += 96 * CC * 2;
  bf16* tmw2b = (bf16*)base;   base += 4 * CC * 32 * 2;
  bf16* tdw2b = (bf16*)base;   base += CC * 64 * 2;
  bf16* tkw2b = (bf16*)base;   base += CC * 16 * 2;
  bf16* taw2b = (bf16*)base;   base += CC * 16 * 2;
  bf16* maw2b = (bf16*)base;   base += CC * 16 * 2;
  bf16* mkw2b = (bf16*)base;   base += CC * 16 * 2;
  // aliases (dead-buffer reuse, verified non-overlapping in time):
  float* ew = kraw;            // fuse2 reads kraw then writes ew at same offs
  float* kfin = (float*)xrgb;  // xrg/xwa bf16 dead before fuse2
  float* kkn = (float*)xkb;    // xk/xv bf16 dead before fuse2
  float* y = xx;               // xx dead after mix4

  auto gemm_m = [&](const bf16* A, const bf16* W, float* Cf, bf16* Cb,
                    int M, int N, int K, int actN) {
    dim3 grid((N + 63) / 64, M / 64);
    gemm_mfma_kernel<<<grid, 256, 0, stream>>>(A, W, Cf, Cb, M, N, K, actN);
  };

  cvt_weights_kernel<<<4480, 256, 0, stream>>>(
      tmw1, wrec, gw1, gw2, wkey, wval, wout,
      tmw1b, wrecb, gw1b, gw2b, wkeyb, wvalb, woutb);
  cvt_small_kernel<<<128, 256, 0, stream>>>(tkw1, mkw1, tdw1, taw1, maw1,
                                            wskb, wswab);
  cvt_small2_kernel<<<256, 256, 0, stream>>>(tmw2, tdw2, tkw2, taw2, maw2, mkw2,
                                             tmw2b, tdw2b, tkw2b, taw2b,
                                             maw2b, mkw2b);
  shift_kernel<<<8192, 256, 0, stream>>>(x, tmx, xx, xxxb);
  gemm_m(xxxb, tmw1b, mix, nullptr, 2048, 128, 1024, 128);   // tanh all
  mix4_kernel<<<2048, 256, 0, stream>>>(x, xx, mix, tmaa, tmw2b,
                                        xrgb, xwab, xkb, xvb);
  gemm_m(xrgb, wrecb, rr, nullptr, 2048, 1024, 1024, 0);
  gemm_m(xrgb, gw1b, nullptr, g1b, 2048, 128, 1024, 128);    // tanh all
  gemm_m(g1b, gw2b, gg, nullptr, 2048, 1024, 128, 0);
  gemm_m(xkb, wkeyb, kraw, nullptr, 2048, 1024, 1024, 0);
  gemm_m(xkb, wskb, out1, nullptr, 2048, 32, 1024, 16);      // tanh cols<16
  gemm_m(xvb, wvalb, vv, nullptr, 2048, 1024, 1024, 0);
  gemm_m(xwab, wswab, out2, nullptr, 2048, 96, 1024, 64);    // tanh cols<64
  fuse2_kernel<<<2048, 256, 0, stream>>>(kraw, out1, out2,
                                         tdw2b, tkw2b, taw2b, maw2b, mkw2b,
                                         tdec, taa5, tmia, tmik,
                                         ew, kfin, kkn, bbo);
  scan_kernel<<<16, 512, 0, stream>>>(rr, ew, kfin, vv, kkn, bbo, y);
  gnout_kernel<<<8192, 256, 0, stream>>>(y, rr, kfin, vv, gg, lnw, lnb, faaa, zb);
  gemm_m(zb, woutb, (float*)d_out, nullptr, 2048, 1024, 1024, 0);
}

// Round 9
// 973.262 us; speedup vs baseline: 2.8249x; 2.8249x over previous
//
#include <hip/hip_runtime.h>
#include <hip/hip_bf16.h>

typedef __hip_bfloat16 bf16;

#define B_ 2
#define T_ 1024
#define C_ 1024
#define H_ 16
#define N_ 64

using short8 = __attribute__((ext_vector_type(8))) short;
using f32x4 = __attribute__((ext_vector_type(4))) float;

__device__ __forceinline__ float us2f(unsigned short u) {
  return __uint_as_float(((unsigned int)u) << 16);
}
__device__ __forceinline__ float bs2f(short s) {
  return __uint_as_float(((unsigned int)(unsigned short)s) << 16);
}
__device__ __forceinline__ bf16 f2bf(float f) { return __float2bfloat16(f); }
__device__ __forceinline__ float sigmoidf_(float x) { return 1.0f / (1.0f + expf(-x)); }
__device__ __forceinline__ float softplusf_(float x) {
  return fmaxf(x, 0.0f) + log1pf(expf(-fabsf(x)));
}
__device__ __forceinline__ void gload_lds16(const float* g, float* l) {
  __builtin_amdgcn_global_load_lds(
      (const __attribute__((address_space(1))) unsigned int*)(const void*)g,
      (__attribute__((address_space(3))) unsigned int*)(void*)l, 16, 0, 0);
}

// ---------------- K0: fused weight fp32->bf16 conversion (big weights) ------
__global__ __launch_bounds__(256) void cvt_weights_kernel(
    const float* __restrict__ s0, const float* __restrict__ s1,
    const float* __restrict__ s2, const float* __restrict__ s3,
    const float* __restrict__ s4, const float* __restrict__ s5,
    const float* __restrict__ s6,
    bf16* __restrict__ d0, bf16* __restrict__ d1, bf16* __restrict__ d2,
    bf16* __restrict__ d3, bf16* __restrict__ d4, bf16* __restrict__ d5,
    bf16* __restrict__ d6) {
  long i4 = (long)blockIdx.x * 256 + threadIdx.x;
  const float* s; bf16* d; long off;
  if (i4 < 32768) { s = s0; d = d0; off = i4; }
  else if (i4 < 294912) { s = s1; d = d1; off = i4 - 32768; }
  else if (i4 < 327680) { s = s2; d = d2; off = i4 - 294912; }
  else if (i4 < 360448) { s = s3; d = d3; off = i4 - 327680; }
  else if (i4 < 622592) { s = s4; d = d4; off = i4 - 360448; }
  else if (i4 < 884736) { s = s5; d = d5; off = i4 - 622592; }
  else { s = s6; d = d6; off = i4 - 884736; }
  float4 v = *(const float4*)(s + off * 4);
  d[off * 4 + 0] = f2bf(v.x);
  d[off * 4 + 1] = f2bf(v.y);
  d[off * 4 + 2] = f2bf(v.z);
  d[off * 4 + 3] = f2bf(v.w);
}

// ---------------- K0b: pack small LoRA-1 weights to bf16 --------------------
__global__ __launch_bounds__(256) void cvt_small_kernel(
    const float* __restrict__ tkw1, const float* __restrict__ mkw1,
    const float* __restrict__ tdw1, const float* __restrict__ taw1,
    const float* __restrict__ maw1,
    bf16* __restrict__ wsk, bf16* __restrict__ wswa) {
  long i4 = (long)blockIdx.x * 256 + threadIdx.x;  // < 32768
  const float* s; bf16* d; long so, dof;
  if (i4 < 4096) { s = tkw1; so = i4; d = wsk; dof = i4; }
  else if (i4 < 8192) { s = mkw1; so = i4 - 4096; d = wsk; dof = i4; }
  else if (i4 < 24576) { s = tdw1; so = i4 - 8192; d = wswa; dof = i4 - 8192; }
  else if (i4 < 28672) { s = taw1; so = i4 - 24576; d = wswa; dof = i4 - 8192; }
  else { s = maw1; so = i4 - 28672; d = wswa; dof = i4 - 8192; }
  float4 v = *(const float4*)(s + so * 4);
  d[dof * 4 + 0] = f2bf(v.x);
  d[dof * 4 + 1] = f2bf(v.y);
  d[dof * 4 + 2] = f2bf(v.z);
  d[dof * 4 + 3] = f2bf(v.w);
}

// ---------------- K0c: LoRA-2 weights to bf16 -------------------------------
__global__ __launch_bounds__(256) void cvt_small2_kernel(
    const float* __restrict__ tmw2, const float* __restrict__ tdw2,
    const float* __restrict__ tkw2, const float* __restrict__ taw2,
    const float* __restrict__ maw2, const float* __restrict__ mkw2,
    bf16* __restrict__ tmw2b, bf16* __restrict__ tdw2b,
    bf16* __restrict__ tkw2b, bf16* __restrict__ taw2b,
    bf16* __restrict__ maw2b, bf16* __restrict__ mkw2b) {
  long i4 = (long)blockIdx.x * 256 + threadIdx.x;  // < 65536
  const float* s; bf16* d; long off;
  if (i4 < 32768) { s = tmw2; d = tmw2b; off = i4; }
  else if (i4 < 49152) { s = tdw2; d = tdw2b; off = i4 - 32768; }
  else if (i4 < 53248) { s = tkw2; d = tkw2b; off = i4 - 49152; }
  else if (i4 < 57344) { s = taw2; d = taw2b; off = i4 - 53248; }
  else if (i4 < 61440) { s = maw2; d = maw2b; off = i4 - 57344; }
  else { s = mkw2; d = mkw2b; off = i4 - 61440; }
  float4 v = *(const float4*)(s + off * 4);
  d[off * 4 + 0] = f2bf(v.x);
  d[off * 4 + 1] = f2bf(v.y);
  d[off * 4 + 2] = f2bf(v.z);
  d[off * 4 + 3] = f2bf(v.w);
}

// ---------------- K1: token shift (writes xx f32, xxx bf16) -----------------
__global__ __launch_bounds__(256) void shift_kernel(
    const float* __restrict__ x, const float* __restrict__ tmx,
    float* __restrict__ xx, bf16* __restrict__ xxxb) {
  long idx = (long)blockIdx.x * 256 + threadIdx.x;  // < B*T*C
  int c = (int)(idx & (C_ - 1));
  int t = (int)((idx >> 10) & (T_ - 1));
  float xv = x[idx];
  float xp = (t > 0) ? x[idx - C_] : 0.0f;
  float d = xp - xv;
  xx[idx] = d;
  xxxb[idx] = f2bf(xv + d * tmx[c]);
}

// ---------------- MFMA GEMM: C = A(bf16 MxK) * W^T (W bf16 NxK) -------------
__global__ __launch_bounds__(256) void gemm_mfma_kernel(
    const bf16* __restrict__ A, const bf16* __restrict__ W,
    float* __restrict__ Cf, bf16* __restrict__ Cb,
    int M, int N, int K, int actN) {
  __shared__ __align__(16) bf16 As[64][72];  // 144B row stride, 16B aligned
  __shared__ __align__(16) bf16 Ws[64][72];
  int tid = threadIdx.x;
  int m0 = blockIdx.y << 6, n0 = blockIdx.x << 6;
  int srow = tid >> 2, skg = (tid & 3) << 4;   // staging: row, 16 bf16 per thread
  int wv = tid >> 6, lane = tid & 63;
  int fr = lane & 15, fq = lane >> 4;
  f32x4 acc0 = {0.f, 0.f, 0.f, 0.f}, acc1 = acc0, acc2 = acc0, acc3 = acc0;
  bool wok = (n0 + srow) < N;
  const bf16* Ap = A + (long)(m0 + srow) * K + skg;
  const bf16* Wp = W + (long)(n0 + srow) * K + skg;
  short8 zz = {0, 0, 0, 0, 0, 0, 0, 0};
  for (int k0 = 0; k0 < K; k0 += 64) {
    *(short8*)&As[srow][skg] = *(const short8*)(Ap + k0);
    *(short8*)&As[srow][skg + 8] = *(const short8*)(Ap + k0 + 8);
    *(short8*)&Ws[srow][skg] = wok ? *(const short8*)(Wp + k0) : zz;
    *(short8*)&Ws[srow][skg + 8] = wok ? *(const short8*)(Wp + k0 + 8) : zz;
    __syncthreads();
#pragma unroll
    for (int kk = 0; kk < 2; kk++) {
      int ko = (fq << 3) + (kk << 5);
      short8 af = *(const short8*)&As[(wv << 4) + fr][ko];
      short8 b0 = *(const short8*)&Ws[fr][ko];
      short8 b1 = *(const short8*)&Ws[16 + fr][ko];
      short8 b2 = *(const short8*)&Ws[32 + fr][ko];
      short8 b3 = *(const short8*)&Ws[48 + fr][ko];
      acc0 = __builtin_amdgcn_mfma_f32_16x16x32_bf16(af, b0, acc0, 0, 0, 0);
      acc1 = __builtin_amdgcn_mfma_f32_16x16x32_bf16(af, b1, acc1, 0, 0, 0);
      acc2 = __builtin_amdgcn_mfma_f32_16x16x32_bf16(af, b2, acc2, 0, 0, 0);
      acc3 = __builtin_amdgcn_mfma_f32_16x16x32_bf16(af, b3, acc3, 0, 0, 0);
    }
    __syncthreads();
  }
  int orow = m0 + (wv << 4) + (fq << 2);
  int ocol = n0 + fr;
  f32x4 av[4] = {acc0, acc1, acc2, acc3};
#pragma unroll
  for (int nt = 0; nt < 4; nt++) {
    int col = ocol + (nt << 4);
    if (col < N) {
#pragma unroll
      for (int r = 0; r < 4; r++) {
        float vvv = av[nt][r];
        if (col < actN) vvv = tanhf(vvv);
        long oi = (long)(orow + r) * N + col;
        if (Cb) Cb[oi] = f2bf(vvv); else Cf[oi] = vvv;
      }
    }
  }
}

// ---------------- K3: deltas + build xrg/xwa/xk/xv (bf16 out) ---------------
__global__ __launch_bounds__(256) void mix4_kernel(
    const float* __restrict__ x, const float* __restrict__ xx,
    const float* __restrict__ mix, const float* __restrict__ tmaa,
    const bf16* __restrict__ w2b,
    bf16* __restrict__ xrg, bf16* __restrict__ xwa,
    bf16* __restrict__ xk, bf16* __restrict__ xv) {
  int m = blockIdx.x;
  int tid = threadIdx.x;
  __shared__ float mrow[128];
  if (tid < 128) mrow[tid] = mix[(long)m * 128 + tid];
  __syncthreads();
#pragma unroll
  for (int cc = 0; cc < 4; cc++) {
    int c = tid + (cc << 8);
    long off = (long)m * C_ + c;
    float xb = x[off];
    float xxv = xx[off];
    float res[4];
#pragma unroll
    for (int f = 0; f < 4; f++) {
      const short8* wp = (const short8*)(w2b + (((long)f * C_ + c) << 5));
      float dl = 0.f;
#pragma unroll
      for (int d8 = 0; d8 < 4; d8++) {
        short8 u = wp[d8];
        int db = (f << 5) + (d8 << 3);
#pragma unroll
        for (int e = 0; e < 8; e++) dl += mrow[db + e] * bs2f(u[e]);
      }
      res[f] = xb + xxv * (tmaa[f * C_ + c] + dl);
    }
    xrg[off] = f2bf(res[0]); xwa[off] = f2bf(res[1]);
    xk[off] = f2bf(res[2]); xv[off] = f2bf(res[3]);
  }
}

// ---------------- K5: stage-2 small GEMMs + gates + per-head kk norm --------
__global__ __launch_bounds__(256) void fuse2_kernel(
    const float* __restrict__ kraw, const float* __restrict__ out1,
    const float* __restrict__ out2,
    const bf16* __restrict__ dw2, const bf16* __restrict__ kkw2,
    const bf16* __restrict__ aw2, const bf16* __restrict__ maw2,
    const bf16* __restrict__ mkw2,
    const float* __restrict__ tdec, const float* __restrict__ taa,
    const float* __restrict__ tma, const float* __restrict__ tmk,
    float* __restrict__ ew, float* __restrict__ kfin,
    float* __restrict__ kkn, float* __restrict__ bbo) {
  int m = blockIdx.x, tid = threadIdx.x;
  __shared__ float w1r[64], kk1r[16], a1r[16], ma1r[16], mk1r[16];
  if (tid < 64) w1r[tid] = out2[(long)m * 96 + tid];
  else if (tid < 80) kk1r[tid - 64] = out1[(long)m * 32 + (tid - 64)];
  else if (tid < 96) a1r[tid - 80] = out2[(long)m * 96 + 64 + (tid - 80)];
  else if (tid < 112) ma1r[tid - 96] = out2[(long)m * 96 + 80 + (tid - 96)];
  else if (tid < 128) mk1r[tid - 112] = out1[(long)m * 32 + 16 + (tid - 112)];
  __syncthreads();
  float kkp[4], av[4], wv[4], kr[4], mkv[4];
  float sumsq = 0.f;
#pragma unroll
  for (int j = 0; j < 4; j++) {
    int c = (tid << 2) + j;
    long off = (long)m * C_ + c;
    float wd = 0.f;
    const short8* dp = (const short8*)(dw2 + ((long)c << 6));
#pragma unroll
    for (int d8 = 0; d8 < 8; d8++) {
      short8 u = dp[d8];
      int db = d8 << 3;
#pragma unroll
      for (int e = 0; e < 8; e++) wd += w1r[db + e] * bs2f(u[e]);
    }
    float w = -softplusf_(-(tdec[c] + wd)) - 0.5f;
    wv[j] = w;
    float kd = 0.f, ad = 0.f, mad = 0.f, mkd = 0.f;
    const short8* kp = (const short8*)(kkw2 + ((long)c << 4));
    const short8* ap = (const short8*)(aw2 + ((long)c << 4));
    const short8* mp = (const short8*)(maw2 + ((long)c << 4));
    const short8* qp = (const short8*)(mkw2 + ((long)c << 4));
#pragma unroll
    for (int d8 = 0; d8 < 2; d8++) {
      short8 u1 = kp[d8], u2 = ap[d8], u3 = mp[d8], u4 = qp[d8];
      int db = d8 << 3;
#pragma unroll
      for (int e = 0; e < 8; e++) {
        kd += kk1r[db + e] * bs2f(u1[e]);
        ad += a1r[db + e] * bs2f(u2[e]);
        mad += ma1r[db + e] * bs2f(u3[e]);
        mkd += mk1r[db + e] * bs2f(u4[e]);
      }
    }
    float krw = kraw[off];
    float kkpre = krw + kd;
    kkp[j] = kkpre;
    sumsq += kkpre * kkpre;
    float a = sigmoidf_(taa[c] + ad);
    av[j] = a;
    float ma = sigmoidf_(tma[c] + mad);
    float mk = sigmoidf_(tmk[c] + mkd);
    mkv[j] = mk;
    kr[j] = krw * (ma + a * (1.f - ma));
  }
  sumsq += __shfl_xor(sumsq, 1);
  sumsq += __shfl_xor(sumsq, 2);
  sumsq += __shfl_xor(sumsq, 4);
  sumsq += __shfl_xor(sumsq, 8);
  float rn = 1.0f / fmaxf(sqrtf(sumsq), 1e-12f);
#pragma unroll
  for (int j = 0; j < 4; j++) {
    int c = (tid << 2) + j;
    long off = (long)m * C_ + c;
    float kknv = kkp[j] * rn;
    kkn[off] = kknv;
    bbo[off] = -kknv * av[j];
    ew[off] = expf(wv[j]);
    kfin[off] = kr[j] * expf(wv[j] * mkv[j]);
  }
}

// ---------------- K6: RWKV-7 scan, LDS double-buffer + async DMA ------------
// 128 blocks x 64 threads (1 wave). block = (b,h,rowgroup of 16 rows).
// Chunk = 16 tokens staged into LDS via global_load_lds (structural prefetch,
// zero VGPR cost). Streams order in LDS: kk,ew,k,bb,r,v. lane=(r<<2)|q:
// row = rg*16+r, 16 consecutive keys [q*16,q*16+16). shfl_xor 1,2 = quad_perm.
#define SCHUNK 16
__global__ __launch_bounds__(64) void scan_kernel(
    const float* __restrict__ rB, const float* __restrict__ ewB,
    const float* __restrict__ kB, const float* __restrict__ vB,
    const float* __restrict__ kkB, const float* __restrict__ bbB,
    float* __restrict__ yB) {
  __shared__ __align__(16) float lds[2][6][SCHUNK * 64];
  int bid = blockIdx.x;          // 0..127
  int bh = bid >> 2;             // 0..31
  int rg = bid & 3;
  int b = bh >> 4, h = bh & 15;
  int lane = threadIdx.x;
  int r = lane >> 2, q = lane & 3;
  int row = (rg << 4) + r;
  int kq = q << 4;
  const long base = ((long)b * T_) * C_ + (h << 6);
  const float* sb0 = kkB + base;
  const float* sb1 = ewB + base;
  const float* sb2 = kB + base;
  const float* sb3 = bbB + base;
  const float* sb4 = rB + base;
  const float* sb5 = vB + base;
  int gl = ((lane >> 4) << 10) + ((lane & 15) << 2);  // token-within-4, 16B piece
  // stage chunk c into buffer buf: 6 streams x 4 instr (4 tokens each)
  auto stage = [&](int c, int buf) {
    int tok0 = c << 4;
#pragma unroll
    for (int j = 0; j < 4; j++) {
      long go = (long)(tok0 + (j << 2)) * C_ + gl;
      int lo = j << 8;
      gload_lds16(sb0 + go, &lds[buf][0][lo]);
      gload_lds16(sb1 + go, &lds[buf][1][lo]);
      gload_lds16(sb2 + go, &lds[buf][2][lo]);
      gload_lds16(sb3 + go, &lds[buf][3][lo]);
      gload_lds16(sb4 + go, &lds[buf][4][lo]);
      gload_lds16(sb5 + go, &lds[buf][5][lo]);
    }
  };
  float S[16];
#pragma unroll
  for (int j = 0; j < 16; j++) S[j] = 0.f;
  stage(0, 0);
  __syncthreads();
  for (int c = 0; c < T_ / SCHUNK; c++) {
    int cb = c & 1;
    if (c + 1 < T_ / SCHUNK) stage(c + 1, cb ^ 1);
    const float* Lkk = &lds[cb][0][0];
    const float* Lew = &lds[cb][1][0];
    const float* Lk = &lds[cb][2][0];
    const float* Lbb = &lds[cb][3][0];
    const float* Lr = &lds[cb][4][0];
    const float* Lv = &lds[cb][5][0];
#pragma unroll 4
    for (int tt = 0; tt < SCHUNK; tt++) {
      int tb = (tt << 6) + kq;
      float4 kk0 = *(const float4*)&Lkk[tb];
      float4 kk1 = *(const float4*)&Lkk[tb + 4];
      float4 kk2 = *(const float4*)&Lkk[tb + 8];
      float4 kk3 = *(const float4*)&Lkk[tb + 12];
      float cv = Lv[(tt << 6) + row];
      // sab partial over own 16 keys (4 independent chains)
      float p0 = S[0] * kk0.x + S[1] * kk0.y + S[2] * kk0.z + S[3] * kk0.w;
      float p1 = S[4] * kk1.x + S[5] * kk1.y + S[6] * kk1.z + S[7] * kk1.w;
      float p2 = S[8] * kk2.x + S[9] * kk2.y + S[10] * kk2.z + S[11] * kk2.w;
      float p3 = S[12] * kk3.x + S[13] * kk3.y + S[14] * kk3.z + S[15] * kk3.w;
      float sab = (p0 + p1) + (p2 + p3);
      sab += __shfl_xor(sab, 1);
      sab += __shfl_xor(sab, 2);
      float4 ew0 = *(const float4*)&Lew[tb];
      float4 ew1 = *(const float4*)&Lew[tb + 4];
      float4 ew2 = *(const float4*)&Lew[tb + 8];
      float4 ew3 = *(const float4*)&Lew[tb + 12];
      float4 bb0 = *(const float4*)&Lbb[tb];
      float4 bb1 = *(const float4*)&Lbb[tb + 4];
      float4 bb2 = *(const float4*)&Lbb[tb + 8];
      float4 bb3 = *(const float4*)&Lbb[tb + 12];
      float4 k0 = *(const float4*)&Lk[tb];
      float4 k1 = *(const float4*)&Lk[tb + 4];
      float4 k2 = *(const float4*)&Lk[tb + 8];
      float4 k3 = *(const float4*)&Lk[tb + 12];
      S[0] = S[0] * ew0.x + sab * bb0.x + cv * k0.x;
      S[1] = S[1] * ew0.y + sab * bb0.y + cv * k0.y;
      S[2] = S[2] * ew0.z + sab * bb0.z + cv * k0.z;
      S[3] = S[3] * ew0.w + sab * bb0.w + cv * k0.w;
      S[4] = S[4] * ew1.x + sab * bb1.x + cv * k1.x;
      S[5] = S[5] * ew1.y + sab * bb1.y + cv * k1.y;
      S[6] = S[6] * ew1.z + sab * bb1.z + cv * k1.z;
      S[7] = S[7] * ew1.w + sab * bb1.w + cv * k1.w;
      S[8] = S[8] * ew2.x + sab * bb2.x + cv * k2.x;
      S[9] = S[9] * ew2.y + sab * bb2.y + cv * k2.y;
      S[10] = S[10] * ew2.z + sab * bb2.z + cv * k2.z;
      S[11] = S[11] * ew2.w + sab * bb2.w + cv * k2.w;
      S[12] = S[12] * ew3.x + sab * bb3.x + cv * k3.x;
      S[13] = S[13] * ew3.y + sab * bb3.y + cv * k3.y;
      S[14] = S[14] * ew3.z + sab * bb3.z + cv * k3.z;
      S[15] = S[15] * ew3.w + sab * bb3.w + cv * k3.w;
      float4 r0 = *(const float4*)&Lr[tb];
      float4 r1 = *(const float4*)&Lr[tb + 4];
      float4 r2 = *(const float4*)&Lr[tb + 8];
      float4 r3 = *(const float4*)&Lr[tb + 12];
      float y0 = S[0] * r0.x + S[1] * r0.y + S[2] * r0.z + S[3] * r0.w;
      float y1 = S[4] * r1.x + S[5] * r1.y + S[6] * r1.z + S[7] * r1.w;
      float y2 = S[8] * r2.x + S[9] * r2.y + S[10] * r2.z + S[11] * r2.w;
      float y3 = S[12] * r3.x + S[13] * r3.y + S[14] * r3.z + S[15] * r3.w;
      float y = (y0 + y1) + (y2 + y3);
      y += __shfl_xor(y, 1);
      y += __shfl_xor(y, 2);
      if (q == 0) yB[base + (long)((c << 4) + tt) * C_ + row] = y;
    }
    __syncthreads();
  }
}

// ---------------- K7: GroupNorm + bonus + gate (bf16 out) -------------------
__global__ __launch_bounds__(256) void gnout_kernel(
    const float* __restrict__ y, const float* __restrict__ r,
    const float* __restrict__ kf, const float* __restrict__ v,
    const float* __restrict__ g,
    const float* __restrict__ lnw, const float* __restrict__ lnb,
    const float* __restrict__ fa, bf16* __restrict__ z) {
  int tid = threadIdx.x;
  int w = tid >> 6, lane = tid & 63;
  int gi = (blockIdx.x << 2) + w;  // (b*T+t)*H + h
  int h = gi & 15, mt = gi >> 4;
  long off = (long)mt * C_ + (h << 6) + lane;
  float yv = y[off];
  float s = yv;
  s += __shfl_xor(s, 1); s += __shfl_xor(s, 2); s += __shfl_xor(s, 4);
  s += __shfl_xor(s, 8); s += __shfl_xor(s, 16); s += __shfl_xor(s, 32);
  float mu = s * (1.0f / 64.0f);
  float d = yv - mu;
  float s2 = d * d;
  s2 += __shfl_xor(s2, 1); s2 += __shfl_xor(s2, 2); s2 += __shfl_xor(s2, 4);
  s2 += __shfl_xor(s2, 8); s2 += __shfl_xor(s2, 16); s2 += __shfl_xor(s2, 32);
  float var = s2 * (1.0f / 64.0f);
  int hc = (h << 6) + lane;
  float dot = r[off] * kf[off] * fa[hc];
  dot += __shfl_xor(dot, 1); dot += __shfl_xor(dot, 2); dot += __shfl_xor(dot, 4);
  dot += __shfl_xor(dot, 8); dot += __shfl_xor(dot, 16); dot += __shfl_xor(dot, 32);
  float yn = d * rsqrtf(var + 0.00064f) * lnw[hc] + lnb[hc];
  z[off] = f2bf((yn + dot * v[off]) * g[off]);
}

extern "C" void kernel_launch(void* const* d_in, const int* in_sizes, int n_in,
                              void* d_out, int out_size, void* d_ws, size_t ws_size,
                              hipStream_t stream) {
  const float* x = (const float*)d_in[0];
  const float* tmx = (const float*)d_in[1];
  const float* tmaa = (const float*)d_in[2];
  const float* tmw1 = (const float*)d_in[3];
  const float* tmw2 = (const float*)d_in[4];
  const float* tdec = (const float*)d_in[5];
  const float* tdw1 = (const float*)d_in[6];
  const float* tdw2 = (const float*)d_in[7];
  const float* taa5 = (const float*)d_in[8];
  const float* taw1 = (const float*)d_in[9];
  const float* taw2 = (const float*)d_in[10];
  const float* tkw1 = (const float*)d_in[11];
  const float* tkw2 = (const float*)d_in[12];
  const float* gw1 = (const float*)d_in[13];
  const float* gw2 = (const float*)d_in[14];
  const float* tmia = (const float*)d_in[15];
  const float* maw1 = (const float*)d_in[16];
  const float* maw2 = (const float*)d_in[17];
  const float* tmik = (const float*)d_in[18];
  const float* mkw1 = (const float*)d_in[19];
  const float* mkw2 = (const float*)d_in[20];
  const float* wrec = (const float*)d_in[21];
  const float* wkey = (const float*)d_in[22];
  const float* wval = (const float*)d_in[23];
  const float* wout = (const float*)d_in[24];
  const float* lnw = (const float*)d_in[25];
  const float* lnb = (const float*)d_in[26];
  const float* faaa = (const float*)d_in[27];

  const long MT = 2048, CC = 1024;
  char* base = (char*)d_ws;
  float* xx = (float*)base;    base += MT * CC * 4;   // also y
  bf16* xxxb = (bf16*)base;    base += MT * CC * 2;
  bf16* xrgb = (bf16*)base;    base += MT * CC * 2;   // ┐ kfin overlays (8MB)
  bf16* xwab = (bf16*)base;    base += MT * CC * 2;   // ┘
  bf16* xkb = (bf16*)base;     base += MT * CC * 2;   // ┐ kkn overlays (8MB)
  bf16* xvb = (bf16*)base;     base += MT * CC * 2;   // ┘
  float* rr = (float*)base;    base += MT * CC * 4;
  float* kraw = (float*)base;  base += MT * CC * 4;   // also ew
  float* vv = (float*)base;    base += MT * CC * 4;
  float* gg = (float*)base;    base += MT * CC * 4;
  float* bbo = (float*)base;   base += MT * CC * 4;
  float* mix = (float*)base;   base += MT * 128 * 4;
  bf16* g1b = (bf16*)base;     base += MT * 128 * 2;
  float* out1 = (float*)base;  base += MT * 32 * 4;   // [kk1|mk1]
  float* out2 = (float*)base;  base += MT * 96 * 4;   // [w1|a1|ma1]
  bf16* zb = (bf16*)base;      base += MT * CC * 2;
  bf16* tmw1b = (bf16*)base;   base += 128 * CC * 2;
  bf16* wrecb = (bf16*)base;   base += CC * CC * 2;
  bf16* gw1b = (bf16*)base;    base += 128 * CC * 2;
  bf16* gw2b = (bf16*)base;    base += CC * 128 * 2;
  bf16* wkeyb = (bf16*)base;   base += CC * CC * 2;
  bf16* wvalb = (bf16*)base;   base += CC * CC * 2;
  bf16* woutb = (bf16*)base;   base += CC * CC * 2;
  bf16* wskb = (bf16*)base;    base += 32 * CC * 2;
  bf16* wswab = (bf16*)base;   base += 96 * CC * 2;
  bf16* tmw2b = (bf16*)base;   base += 4 * CC * 32 * 2;
  bf16* tdw2b = (bf16*)base;   base += CC * 64 * 2;
  bf16* tkw2b = (bf16*)base;   base += CC * 16 * 2;
  bf16* taw2b = (bf16*)base;   base += CC * 16 * 2;
  bf16* maw2b = (bf16*)base;   base += CC * 16 * 2;
  bf16* mkw2b = (bf16*)base;   base += CC * 16 * 2;
  // aliases (dead-buffer reuse, verified non-overlapping in time):
  float* ew = kraw;            // fuse2 reads kraw then writes ew at same offs
  float* kfin = (float*)xrgb;  // xrg/xwa bf16 dead before fuse2
  float* kkn = (float*)xkb;    // xk/xv bf16 dead before fuse2
  float* y = xx;               // xx dead after mix4

  auto gemm_m = [&](const bf16* A, const bf16* W, float* Cf, bf16* Cb,
                    int M, int N, int K, int actN) {
    dim3 grid((N + 63) / 64, M / 64);
    gemm_mfma_kernel<<<grid, 256, 0, stream>>>(A, W, Cf, Cb, M, N, K, actN);
  };

  cvt_weights_kernel<<<4480, 256, 0, stream>>>(
      tmw1, wrec, gw1, gw2, wkey, wval, wout,
      tmw1b, wrecb, gw1b, gw2b, wkeyb, wvalb, woutb);
  cvt_small_kernel<<<128, 256, 0, stream>>>(tkw1, mkw1, tdw1, taw1, maw1,
                                            wskb, wswab);
  cvt_small2_kernel<<<256, 256, 0, stream>>>(tmw2, tdw2, tkw2, taw2, maw2, mkw2,
                                             tmw2b, tdw2b, tkw2b, taw2b,
                                             maw2b, mkw2b);
  shift_kernel<<<8192, 256, 0, stream>>>(x, tmx, xx, xxxb);
  gemm_m(xxxb, tmw1b, mix, nullptr, 2048, 128, 1024, 128);   // tanh all
  mix4_kernel<<<2048, 256, 0, stream>>>(x, xx, mix, tmaa, tmw2b,
                                        xrgb, xwab, xkb, xvb);
  gemm_m(xrgb, wrecb, rr, nullptr, 2048, 1024, 1024, 0);
  gemm_m(xrgb, gw1b, nullptr, g1b, 2048, 128, 1024, 128);    // tanh all
  gemm_m(g1b, gw2b, gg, nullptr, 2048, 1024, 128, 0);
  gemm_m(xkb, wkeyb, kraw, nullptr, 2048, 1024, 1024, 0);
  gemm_m(xkb, wskb, out1, nullptr, 2048, 32, 1024, 16);      // tanh cols<16
  gemm_m(xvb, wvalb, vv, nullptr, 2048, 1024, 1024, 0);
  gemm_m(xwab, wswab, out2, nullptr, 2048, 96, 1024, 64);    // tanh cols<64
  fuse2_kernel<<<2048, 256, 0, stream>>>(kraw, out1, out2,
                                         tdw2b, tkw2b, taw2b, maw2b, mkw2b,
                                         tdec, taa5, tmia, tmik,
                                         ew, kfin, kkn, bbo);
  scan_kernel<<<128, 64, 0, stream>>>(rr, ew, kfin, vv, kkn, bbo, y);
  gnout_kernel<<<8192, 256, 0, stream>>>(y, rr, kfin, vv, gg, lnw, lnb, faaa, zb);
  gemm_m(zb, woutb, (float*)d_out, nullptr, 2048, 1024, 1024, 0);
}